// Round 28
// baseline (33.436 us; speedup 1.0000x reference)
//
#include <hip/hip_runtime.h>
#include <stdint.h>

// Problem constants
#define N_ANCHOR 2048
#define DIM 128
#define NEG_PER 15
#define NZ 32768                    // 2048*16 candidate rows
#define INV_TEMP 3.3333333333333335f
#define LN2 0.6931471805599453f
#define TOTAL_ELEMS 67108864.0f
#define PRE (INV_TEMP * 0.5f)       // anchor prescale: MFMA output y = l/2

#define NT 8                        // 8 phases of 32 cols, 4-buffer ring
#define NBLK 1024                   // 8 rb x 128 cg
#define NPREP 1088                  // 64 anchor tiles + 1024 z tiles

using bf16x8 = __attribute__((ext_vector_type(8))) __bf16;
using f32x16 = __attribute__((ext_vector_type(16))) float;
using f32x2  = __attribute__((ext_vector_type(2))) float;
using u16x8  = __attribute__((ext_vector_type(8))) unsigned short;

// ---------- helpers ----------
static __device__ __forceinline__ unsigned short f2bf(float f) {
  union { float f; unsigned u; } v; v.f = f;
  unsigned r = v.u + 0x7FFF + ((v.u >> 16) & 1);   // round-to-nearest-even
  return (unsigned short)(r >> 16);
}
static __device__ __forceinline__ float bf2f(unsigned short u) {
  union { unsigned u; float f; } v; v.u = ((unsigned)u) << 16;
  return v.f;
}
static __device__ __forceinline__ void gload_lds16(const void* g, void* l) {
  __builtin_amdgcn_global_load_lds(
      (const __attribute__((address_space(1))) void*)g,
      (__attribute__((address_space(3))) void*)l, 16, 0, 0);
}

// ---------- kernel 1: prep — register-direct frag writeout (verbatim R27) -
__global__ __launch_bounds__(256) void prep_kernel(
    const float* __restrict__ anchor, const float* __restrict__ pos,
    const float* __restrict__ neg, unsigned short* __restrict__ aF,
    unsigned short* __restrict__ zF, float* __restrict__ dpart) {
  __shared__ unsigned short lz[32 * 132];
  __shared__ float wna[4], wdd[4];
  const int T = blockIdx.x, t = threadIdx.x;
  const int r = t >> 3, q = t & 7;       // 8 threads per row, 16 dims each
  const float* src;
  float pre;
  unsigned short* dst;
  if (T < 64) {
    src = anchor + (size_t)(T * 32 + r) * DIM;
    pre = PRE;
    dst = aF + (size_t)T * 4096;
  } else {
    int c = (T - 64) * 32 + r;
    int j = c >> 4, k = c & 15;
    src = (k == 0) ? (pos + (size_t)j * DIM)
                   : (neg + (size_t)(j * NEG_PER + k - 1) * DIM);
    pre = 1.0f;
    dst = zF + (size_t)(T - 64) * 4096;
  }
  float4 v[4];
  #pragma unroll
  for (int m = 0; m < 4; ++m) v[m] = *(const float4*)(src + q * 16 + m * 4);
  float s = 0.f;
  #pragma unroll
  for (int m = 0; m < 4; ++m)
    s += v[m].x * v[m].x + v[m].y * v[m].y + v[m].z * v[m].z + v[m].w * v[m].w;
  s += __shfl_xor(s, 1); s += __shfl_xor(s, 2); s += __shfl_xor(s, 4);
  float sc = pre / fmaxf(sqrtf(s), 1e-12f);

  ushort4 w[4];
  #pragma unroll
  for (int m = 0; m < 4; ++m) {
    w[m].x = f2bf(v[m].x * sc); w[m].y = f2bf(v[m].y * sc);
    w[m].z = f2bf(v[m].z * sc); w[m].w = f2bf(v[m].w * sc);
  }

  // register-direct frag-major global stores (two 16B per thread)
  {
    u16x8 lo = {w[0].x, w[0].y, w[0].z, w[0].w, w[1].x, w[1].y, w[1].z, w[1].w};
    u16x8 hi = {w[2].x, w[2].y, w[2].z, w[2].w, w[3].x, w[3].y, w[3].z, w[3].w};
    *(u16x8*)(dst + (q * 64 + r) * 8)      = lo;   // ks=q, kh=0
    *(u16x8*)(dst + (q * 64 + 32 + r) * 8) = hi;   // ks=q, kh=1
  }

  if (T >= 64) {                         // ---- fused diagonal (R18) ----
    #pragma unroll
    for (int m = 0; m < 4; ++m)
      *(ushort4*)(lz + r * 132 + q * 16 + m * 4) = w[m];
    __syncthreads();

    const int a = t >> 7;                // anchor sub-group 0/1
    const int d = t & 127;
    float zs = 0.f;
    #pragma unroll
    for (int rr = 0; rr < 16; ++rr)
      zs += bf2f(lz[(a * 16 + rr) * 132 + d]);   // 2-way bank alias: free
    const int j = (T - 64) * 2 + a;
    float av = anchor[(size_t)j * DIM + d];      // coalesced 512B per group
    float pna = av * av, pdd = av * zs;
    #pragma unroll
    for (int o = 32; o >= 1; o >>= 1) {
      pna += __shfl_xor(pna, o);
      pdd += __shfl_xor(pdd, o);
    }
    if ((t & 63) == 0) { wna[t >> 6] = pna; wdd[t >> 6] = pdd; }
    __syncthreads();
    if ((t & 127) == 0) {
      int w0 = t >> 6;                   // 0 or 2
      float na = wna[w0] + wna[w0 + 1];
      float dd = wdd[w0] + wdd[w0 + 1];
      dpart[j] = PRE * dd / fmaxf(sqrtf(na), 1e-12f);
    }
  }
}

// ---------- kernel 2: fused GEMM + loss — 4 INDEPENDENT MFMA CHAINS -------
// R27 post-mortem: per-wave-phase issue work ~250cyc vs observed ~750cyc,
// and all schedule/occupancy levers null. Suspect: MFMA RAW latency on the
// accumulator with only 2 chains (dep-distance 2) and 2 waves/SIMD.
// Isolated fix: K-parity split -> 4 independent chains (dep-distance 4),
// combined with two f32x16 adds before the epilogue (exact f32 reassoc).
__global__ __launch_bounds__(256) void gemm_loss_kernel(
    const unsigned short* __restrict__ aF,
    const unsigned short* __restrict__ zF,
    float* __restrict__ partial) {
  __shared__ __align__(16) unsigned short Bs[4][512 * 8];   // 4 x 8 KB ring
  __shared__ float red[4];

  const int t    = threadIdx.x;
  const int bid  = blockIdx.x;
  const int rb   = bid >> 7;       // 8 row-blocks of 256
  const int cgi  = bid & 127;      // 128 col-groups of 256
  const int wave = t >> 6;
  const int lane = t & 63;

  // staging source: tile tt (32 cols) = frag-major 8KB tile; slot s=it*256+t
  const unsigned short* pB = zF + (size_t)(cgi * NT) * 4096 + t * 8;

#define STAGE_B(buf, tt)                                                   \
  {                                                                        \
    const unsigned short* bg = pB + (size_t)(tt) * 4096;                   \
    gload_lds16(bg,        (buf) + (wave * 64) * 8);                       \
    gload_lds16(bg + 2048, (buf) + (256 + wave * 64) * 8);                 \
  }

  STAGE_B(Bs[0], 0)
  STAGE_B(Bs[1], 1)

  // A fragments from frag-major aF (coalesced: lane*16B)
  bf16x8 af[2][8];
  {
    const unsigned short* Ab =
        aF + (size_t)(rb * 8 + wave * 2) * 4096 + lane * 8;
    #pragma unroll
    for (int i = 0; i < 2; ++i)
      #pragma unroll
      for (int ks = 0; ks < 8; ++ks)
        af[i][ks] = *(const bf16x8*)(Ab + i * 4096 + ks * 512);
  }

  f32x2 ya = 0.f, yb = 0.f;                           // Sum(y)
  f32x2 s1a = 0.f, s1b = 0.f;                         // Sum(y^2)

  #pragma unroll 1
  for (int tt = 0; tt < NT; ++tt) {
    if (tt + 2 < NT) {
      STAGE_B(Bs[(tt + 2) & 3], tt + 2)
      asm volatile("s_waitcnt vmcnt(4)" ::: "memory");
    } else if (tt + 2 == NT) {
      asm volatile("s_waitcnt vmcnt(2)" ::: "memory");
    } else {
      asm volatile("s_waitcnt vmcnt(0)" ::: "memory");
    }
    __builtin_amdgcn_s_barrier();    // ONE barrier per phase (ring-safe)
    asm volatile("" ::: "memory");

    const unsigned short* Bb = Bs[tt & 3];

    // 4 independent accumulator chains (K-parity split)
    f32x16 a0e = 0.0f, a0o = 0.0f, a1e = 0.0f, a1o = 0.0f;
    __builtin_amdgcn_s_setprio(1);
    #pragma unroll
    for (int ks = 0; ks < 8; ks += 2) {
      bf16x8 be = *(const bf16x8*)(Bb + (ks * 64 + lane) * 8);
      bf16x8 bo = *(const bf16x8*)(Bb + ((ks + 1) * 64 + lane) * 8);
      a0e = __builtin_amdgcn_mfma_f32_32x32x16_bf16(af[0][ks],     be, a0e, 0, 0, 0);
      a1e = __builtin_amdgcn_mfma_f32_32x32x16_bf16(af[1][ks],     be, a1e, 0, 0, 0);
      a0o = __builtin_amdgcn_mfma_f32_32x32x16_bf16(af[0][ks + 1], bo, a0o, 0, 0, 0);
      a1o = __builtin_amdgcn_mfma_f32_32x32x16_bf16(af[1][ks + 1], bo, a1o, 0, 0, 0);
    }
    __builtin_amdgcn_s_setprio(0);

    f32x16 acc0 = a0e + a0o;
    f32x16 acc1 = a1e + a1o;

    // epilogue: 2 VALU/elem — ya += p ; s1 = fma(p,p,s1)  (f32x2 packed)
    #pragma unroll
    for (int e = 0; e < 16; e += 4) {
      f32x2 p0 = {acc0[e], acc0[e + 1]};
      f32x2 p1 = {acc0[e + 2], acc0[e + 3]};
      ya += p0; yb += p1;
      s1a = __builtin_elementwise_fma(p0, p0, s1a);
      s1b = __builtin_elementwise_fma(p1, p1, s1b);
    }
    #pragma unroll
    for (int e = 0; e < 16; e += 4) {
      f32x2 p0 = {acc1[e], acc1[e + 1]};
      f32x2 p1 = {acc1[e + 2], acc1[e + 3]};
      ya += p0; yb += p1;
      s1a = __builtin_elementwise_fma(p0, p0, s1a);
      s1b = __builtin_elementwise_fma(p1, p1, s1b);
    }
  }

  float SY = (ya.x + ya.y) + (yb.x + yb.y);
  float S1 = (s1a.x + s1a.y) + (s1b.x + s1b.y);
  float local = SY + 0.5f * S1;
  #pragma unroll
  for (int o = 32; o >= 1; o >>= 1) local += __shfl_xor(local, o);
  if (lane == 0) red[wave] = local;
  __syncthreads();
  if (t == 0) partial[bid] = (red[0] + red[1]) + (red[2] + red[3]);
}

// ---------- kernel 3: final reduction (verbatim R25) ----------------------
// out = LN2 + (Sum partial - 2*Sum dpart) / N
__global__ __launch_bounds__(256) void reduce_kernel(
    const float* __restrict__ partial, const float* __restrict__ dpart,
    float* __restrict__ out) {
  __shared__ float red[4];
  const int t = threadIdx.x;
  float s = 0.0f;
  #pragma unroll
  for (int i = 0; i < NBLK / 256; ++i) s += partial[i * 256 + t];
  #pragma unroll
  for (int i = 0; i < N_ANCHOR / 256; ++i) s -= 2.0f * dpart[i * 256 + t];
  #pragma unroll
  for (int o = 32; o >= 1; o >>= 1) s += __shfl_xor(s, o);
  if ((t & 63) == 0) red[t >> 6] = s;
  __syncthreads();
  if (t == 0)
    out[0] = LN2 +
             ((red[0] + red[1]) + (red[2] + red[3])) * (1.0f / TOTAL_ELEMS);
}

extern "C" void kernel_launch(void* const* d_in, const int* in_sizes, int n_in,
                              void* d_out, int out_size, void* d_ws, size_t ws_size,
                              hipStream_t stream) {
  const float* anchor = (const float*)d_in[0];
  const float* pos    = (const float*)d_in[1];
  const float* neg    = (const float*)d_in[2];
  char* ws = (char*)d_ws;
  unsigned short* aF = (unsigned short*)ws;                      // 512 KB
  unsigned short* zF = (unsigned short*)(ws + 524288);           // 8 MB
  char* base = ws + 524288 + 8388608;
  float* partial = (float*)base;                                 // 4 KB
  float* dpart   = (float*)(base + 4096);                        // 8 KB

  prep_kernel<<<dim3(NPREP), dim3(256), 0, stream>>>(anchor, pos, neg,
                                                     aF, zF, dpart);
  gemm_loss_kernel<<<dim3(NBLK), dim3(256), 0, stream>>>(aF, zF, partial);
  reduce_kernel<<<dim3(1), dim3(256), 0, stream>>>(partial, dpart,
                                                   (float*)d_out);
}

// Round 29
// 31.437 us; speedup vs baseline: 1.0636x; 1.0636x over previous
//
#include <hip/hip_runtime.h>
#include <stdint.h>

// Problem constants
#define N_ANCHOR 2048
#define DIM 128
#define NEG_PER 15
#define NZ 32768                    // 2048*16 candidate rows
#define INV_TEMP 3.3333333333333335f
#define LN2 0.6931471805599453f
#define TOTAL_ELEMS 67108864.0f
#define PRE (INV_TEMP * 0.5f)       // anchor prescale: MFMA output y = l/2

#define NT 16                       // 16 phases of 32 cols, 4-buffer ring
#define NBLK 512                    // 8 rb x 64 cg (CPB=512)
#define NPREP 1088                  // 64 anchor tiles + 1024 z tiles

using bf16x8 = __attribute__((ext_vector_type(8))) __bf16;
using f32x16 = __attribute__((ext_vector_type(16))) float;
using f32x2  = __attribute__((ext_vector_type(2))) float;
using u16x8  = __attribute__((ext_vector_type(8))) unsigned short;

// ---------- helpers ----------
static __device__ __forceinline__ unsigned short f2bf(float f) {
  union { float f; unsigned u; } v; v.f = f;
  unsigned r = v.u + 0x7FFF + ((v.u >> 16) & 1);   // round-to-nearest-even
  return (unsigned short)(r >> 16);
}
static __device__ __forceinline__ float bf2f(unsigned short u) {
  union { unsigned u; float f; } v; v.u = ((unsigned)u) << 16;
  return v.f;
}
static __device__ __forceinline__ void gload_lds16(const void* g, void* l) {
  __builtin_amdgcn_global_load_lds(
      (const __attribute__((address_space(1))) void*)g,
      (__attribute__((address_space(3))) void*)l, 16, 0, 0);
}

// ---------- kernel 1: prep — register-direct frag writeout (verbatim R27) -
__global__ __launch_bounds__(256) void prep_kernel(
    const float* __restrict__ anchor, const float* __restrict__ pos,
    const float* __restrict__ neg, unsigned short* __restrict__ aF,
    unsigned short* __restrict__ zF, float* __restrict__ dpart) {
  __shared__ unsigned short lz[32 * 132];
  __shared__ float wna[4], wdd[4];
  const int T = blockIdx.x, t = threadIdx.x;
  const int r = t >> 3, q = t & 7;       // 8 threads per row, 16 dims each
  const float* src;
  float pre;
  unsigned short* dst;
  if (T < 64) {
    src = anchor + (size_t)(T * 32 + r) * DIM;
    pre = PRE;
    dst = aF + (size_t)T * 4096;
  } else {
    int c = (T - 64) * 32 + r;
    int j = c >> 4, k = c & 15;
    src = (k == 0) ? (pos + (size_t)j * DIM)
                   : (neg + (size_t)(j * NEG_PER + k - 1) * DIM);
    pre = 1.0f;
    dst = zF + (size_t)(T - 64) * 4096;
  }
  float4 v[4];
  #pragma unroll
  for (int m = 0; m < 4; ++m) v[m] = *(const float4*)(src + q * 16 + m * 4);
  float s = 0.f;
  #pragma unroll
  for (int m = 0; m < 4; ++m)
    s += v[m].x * v[m].x + v[m].y * v[m].y + v[m].z * v[m].z + v[m].w * v[m].w;
  s += __shfl_xor(s, 1); s += __shfl_xor(s, 2); s += __shfl_xor(s, 4);
  float sc = pre / fmaxf(sqrtf(s), 1e-12f);

  ushort4 w[4];
  #pragma unroll
  for (int m = 0; m < 4; ++m) {
    w[m].x = f2bf(v[m].x * sc); w[m].y = f2bf(v[m].y * sc);
    w[m].z = f2bf(v[m].z * sc); w[m].w = f2bf(v[m].w * sc);
  }

  // register-direct frag-major global stores (two 16B per thread)
  {
    u16x8 lo = {w[0].x, w[0].y, w[0].z, w[0].w, w[1].x, w[1].y, w[1].z, w[1].w};
    u16x8 hi = {w[2].x, w[2].y, w[2].z, w[2].w, w[3].x, w[3].y, w[3].z, w[3].w};
    *(u16x8*)(dst + (q * 64 + r) * 8)      = lo;   // ks=q, kh=0
    *(u16x8*)(dst + (q * 64 + 32 + r) * 8) = hi;   // ks=q, kh=1
  }

  if (T >= 64) {                         // ---- fused diagonal (R18) ----
    #pragma unroll
    for (int m = 0; m < 4; ++m)
      *(ushort4*)(lz + r * 132 + q * 16 + m * 4) = w[m];
    __syncthreads();

    const int a = t >> 7;                // anchor sub-group 0/1
    const int d = t & 127;
    float zs = 0.f;
    #pragma unroll
    for (int rr = 0; rr < 16; ++rr)
      zs += bf2f(lz[(a * 16 + rr) * 132 + d]);   // 2-way bank alias: free
    const int j = (T - 64) * 2 + a;
    float av = anchor[(size_t)j * DIM + d];      // coalesced 512B per group
    float pna = av * av, pdd = av * zs;
    #pragma unroll
    for (int o = 32; o >= 1; o >>= 1) {
      pna += __shfl_xor(pna, o);
      pdd += __shfl_xor(pdd, o);
    }
    if ((t & 63) == 0) { wna[t >> 6] = pna; wdd[t >> 6] = pdd; }
    __syncthreads();
    if ((t & 127) == 0) {
      int w0 = t >> 6;                   // 0 or 2
      float na = wna[w0] + wna[w0 + 1];
      float dd = wdd[w0] + wdd[w0 + 1];
      dpart[j] = PRE * dd / fmaxf(sqrtf(na), 1e-12f);
    }
  }
}

// ---------- kernel 2: fused GEMM + loss — CPB=512 (A-traffic halved) ------
// R28 post-mortem: 4-chain split regressed; reverted. Last untested axis in
// the current era: A-frag re-load traffic (64 of 128 MB L2 total). Single
// change vs R27: CG=64 / CPB=512 / NT=16, grid 512. A-traffic 32 MB.
// Pipeline/epilogue/LDS verbatim R27 (ring, stage-ahead-2, counted vmcnt).
__global__ __launch_bounds__(256) void gemm_loss_kernel(
    const unsigned short* __restrict__ aF,
    const unsigned short* __restrict__ zF,
    float* __restrict__ partial) {
  __shared__ __align__(16) unsigned short Bs[4][512 * 8];   // 4 x 8 KB ring
  __shared__ float red[4];

  const int t    = threadIdx.x;
  const int bid  = blockIdx.x;
  const int rb   = bid >> 6;       // 8 row-blocks of 256
  const int cgi  = bid & 63;       // 64 col-groups of 512
  const int wave = t >> 6;
  const int lane = t & 63;

  // staging source: tile tt (32 cols) = frag-major 8KB tile; slot s=it*256+t
  const unsigned short* pB = zF + (size_t)(cgi * NT) * 4096 + t * 8;

#define STAGE_B(buf, tt)                                                   \
  {                                                                        \
    const unsigned short* bg = pB + (size_t)(tt) * 4096;                   \
    gload_lds16(bg,        (buf) + (wave * 64) * 8);                       \
    gload_lds16(bg + 2048, (buf) + (256 + wave * 64) * 8);                 \
  }

  STAGE_B(Bs[0], 0)
  STAGE_B(Bs[1], 1)

  // A fragments from frag-major aF (coalesced: lane*16B)
  bf16x8 af[2][8];
  {
    const unsigned short* Ab =
        aF + (size_t)(rb * 8 + wave * 2) * 4096 + lane * 8;
    #pragma unroll
    for (int i = 0; i < 2; ++i)
      #pragma unroll
      for (int ks = 0; ks < 8; ++ks)
        af[i][ks] = *(const bf16x8*)(Ab + i * 4096 + ks * 512);
  }

  f32x2 ya = 0.f, yb = 0.f;                           // Sum(y)
  f32x2 s1a = 0.f, s1b = 0.f;                         // Sum(y^2)

  #pragma unroll 1
  for (int tt = 0; tt < NT; ++tt) {
    if (tt + 2 < NT) {
      STAGE_B(Bs[(tt + 2) & 3], tt + 2)
      asm volatile("s_waitcnt vmcnt(4)" ::: "memory");
    } else if (tt + 2 == NT) {
      asm volatile("s_waitcnt vmcnt(2)" ::: "memory");
    } else {
      asm volatile("s_waitcnt vmcnt(0)" ::: "memory");
    }
    __builtin_amdgcn_s_barrier();    // ONE barrier per phase (ring-safe)
    asm volatile("" ::: "memory");

    const unsigned short* Bb = Bs[tt & 3];

    f32x16 acc0 = 0.0f, acc1 = 0.0f;
    __builtin_amdgcn_s_setprio(1);
    #pragma unroll
    for (int ks = 0; ks < 8; ++ks) {
      bf16x8 b = *(const bf16x8*)(Bb + (ks * 64 + lane) * 8);
      acc0 = __builtin_amdgcn_mfma_f32_32x32x16_bf16(af[0][ks], b, acc0, 0, 0, 0);
      acc1 = __builtin_amdgcn_mfma_f32_32x32x16_bf16(af[1][ks], b, acc1, 0, 0, 0);
    }
    __builtin_amdgcn_s_setprio(0);

    // epilogue: 2 VALU/elem — ya += p ; s1 = fma(p,p,s1)  (f32x2 packed)
    #pragma unroll
    for (int e = 0; e < 16; e += 4) {
      f32x2 p0 = {acc0[e], acc0[e + 1]};
      f32x2 p1 = {acc0[e + 2], acc0[e + 3]};
      ya += p0; yb += p1;
      s1a = __builtin_elementwise_fma(p0, p0, s1a);
      s1b = __builtin_elementwise_fma(p1, p1, s1b);
    }
    #pragma unroll
    for (int e = 0; e < 16; e += 4) {
      f32x2 p0 = {acc1[e], acc1[e + 1]};
      f32x2 p1 = {acc1[e + 2], acc1[e + 3]};
      ya += p0; yb += p1;
      s1a = __builtin_elementwise_fma(p0, p0, s1a);
      s1b = __builtin_elementwise_fma(p1, p1, s1b);
    }
  }

  float SY = (ya.x + ya.y) + (yb.x + yb.y);
  float S1 = (s1a.x + s1a.y) + (s1b.x + s1b.y);
  float local = SY + 0.5f * S1;
  #pragma unroll
  for (int o = 32; o >= 1; o >>= 1) local += __shfl_xor(local, o);
  if (lane == 0) red[wave] = local;
  __syncthreads();
  if (t == 0) partial[bid] = (red[0] + red[1]) + (red[2] + red[3]);
}

// ---------- kernel 3: final reduction -------------------------------------
// out = LN2 + (Sum partial - 2*Sum dpart) / N
__global__ __launch_bounds__(256) void reduce_kernel(
    const float* __restrict__ partial, const float* __restrict__ dpart,
    float* __restrict__ out) {
  __shared__ float red[4];
  const int t = threadIdx.x;
  float s = 0.0f;
  #pragma unroll
  for (int i = 0; i < NBLK / 256; ++i) s += partial[i * 256 + t];
  #pragma unroll
  for (int i = 0; i < N_ANCHOR / 256; ++i) s -= 2.0f * dpart[i * 256 + t];
  #pragma unroll
  for (int o = 32; o >= 1; o >>= 1) s += __shfl_xor(s, o);
  if ((t & 63) == 0) red[t >> 6] = s;
  __syncthreads();
  if (t == 0)
    out[0] = LN2 +
             ((red[0] + red[1]) + (red[2] + red[3])) * (1.0f / TOTAL_ELEMS);
}

extern "C" void kernel_launch(void* const* d_in, const int* in_sizes, int n_in,
                              void* d_out, int out_size, void* d_ws, size_t ws_size,
                              hipStream_t stream) {
  const float* anchor = (const float*)d_in[0];
  const float* pos    = (const float*)d_in[1];
  const float* neg    = (const float*)d_in[2];
  char* ws = (char*)d_ws;
  unsigned short* aF = (unsigned short*)ws;                      // 512 KB
  unsigned short* zF = (unsigned short*)(ws + 524288);           // 8 MB
  char* base = ws + 524288 + 8388608;
  float* partial = (float*)base;                                 // 2 KB
  float* dpart   = (float*)(base + 4096);                        // 8 KB

  prep_kernel<<<dim3(NPREP), dim3(256), 0, stream>>>(anchor, pos, neg,
                                                     aF, zF, dpart);
  gemm_loss_kernel<<<dim3(NBLK), dim3(256), 0, stream>>>(aF, zF, partial);
  reduce_kernel<<<dim3(1), dim3(256), 0, stream>>>(partial, dpart,
                                                   (float*)d_out);
}